// Round 4
// baseline (254.294 us; speedup 1.0000x reference)
//
#include <hip/hip_runtime.h>
#include <hip/hip_bf16.h>

typedef unsigned short u16;
typedef u16 u16x8 __attribute__((ext_vector_type(8)));
typedef __bf16 bf16x8 __attribute__((ext_vector_type(8)));
typedef float f32x4 __attribute__((ext_vector_type(4)));

__device__ __forceinline__ u16 f2bf(float f) {
  unsigned u = __float_as_uint(f);
  u += 0x7FFFu + ((u >> 16) & 1u);   // round-to-nearest-even
  return (u16)(u >> 16);
}
__device__ __forceinline__ float bf2f(u16 h) {
  return __uint_as_float(((unsigned)h) << 16);
}
__device__ __forceinline__ float tanh_fast(float x) {
  float t = __expf(2.0f * x);
  return 1.0f - 2.0f / (t + 1.0f);
}
__device__ __forceinline__ float sigmoid_fast(float x) {
  return 1.0f / (1.0f + __expf(-x));
}

__device__ __forceinline__ u16x8 pack8(float4 a, float4 b) {
  u16x8 o;
  o[0] = f2bf(a.x); o[1] = f2bf(a.y); o[2] = f2bf(a.z); o[3] = f2bf(a.w);
  o[4] = f2bf(b.x); o[5] = f2bf(b.y); o[6] = f2bf(b.z); o[7] = f2bf(b.w);
  return o;
}
// interleaved [e][2] fp32 -> bf16 diffs (class1 - class0), 8 outputs from 16 floats
__device__ __forceinline__ u16x8 pack8d(const float4* v) {
  u16x8 o;
  o[0] = f2bf(v[0].y - v[0].x); o[1] = f2bf(v[0].w - v[0].z);
  o[2] = f2bf(v[1].y - v[1].x); o[3] = f2bf(v[1].w - v[1].z);
  o[4] = f2bf(v[2].y - v[2].x); o[5] = f2bf(v[2].w - v[2].z);
  o[6] = f2bf(v[3].y - v[3].x); o[7] = f2bf(v[3].w - v[3].z);
  return o;
}

// ---------------- bf16 MFMA GEMM, C = A[M,K] * B[N,K]^T ----------------
// R2-proven structure: VGPR-pipelined staging (loads for tile k+1 issued right
// after the LDS-ready barrier, in flight across the whole ds_read+MFMA section;
// forced vmcnt(0)-before-barrier coincides with ds_write needing the regs).
// fp32->bf16 conversion fused into staging (no separate prep pass):
//   AMODE 0: A is bf16      | AMODE 1: A is fp32, convert on stage
//   BMODE 0: B is bf16      | BMODE 1: B is fp32, convert on stage
//   BMODE 2: B is attn_W [N][K][2] fp32, stage bf16(W[..1]-W[..0])
// EP 0: outb = bf16(tanh(x + bias[col]))
// EP 1: att = sigmoid(x + (bias[2c+1]-bias[2c])); outf = att; sa = bf16(obs*att)
template <int BM, int BN, int AMODE, int BMODE, int EP>
__global__ __launch_bounds__(256)
void gemm_f(const void* __restrict__ Avp, const void* __restrict__ Bvp,
            int N, int K,
            const float* __restrict__ bias,
            u16* __restrict__ outb, float* __restrict__ outf,
            const float* __restrict__ obs, u16* __restrict__ sa) {
  constexpr int CA = BM / 64;          // staging chunks per thread (A)
  constexpr int CB = BN / 64;          // staging chunks per thread (B)
  constexpr int MI = BM / 32;          // 16-row frags per wave (M)
  constexpr int NJ = BN / 32;          // 16-col frags per wave (N)

  __shared__ __align__(16) u16 As[BM * 32];
  __shared__ __align__(16) u16 Bs[BN * 32];

  const int tid = threadIdx.x;
  const int lane = tid & 63;
  const int wave = tid >> 6;
  const int bm = blockIdx.x, bn = blockIdx.y;

  const int sr = tid >> 2;             // staging row base 0..63
  const int c0 = (tid & 3) * 8;        // element offset within 32-wide K slab

  const u16* gA16[CA]; const float* gA32[CA];
  const u16* gB16[CB]; const float* gB32[CB];
#pragma unroll
  for (int q = 0; q < CA; ++q) {
    const size_t row = bm * BM + sr + q * 64;
    if constexpr (AMODE == 0) gA16[q] = (const u16*)Avp + row * K + c0;
    else                      gA32[q] = (const float*)Avp + row * K + c0;
  }
#pragma unroll
  for (int q = 0; q < CB; ++q) {
    const size_t row = bn * BN + sr + q * 64;
    if constexpr (BMODE == 0)      gB16[q] = (const u16*)Bvp + row * K + c0;
    else if constexpr (BMODE == 1) gB32[q] = (const float*)Bvp + row * K + c0;
    else                           gB32[q] = (const float*)Bvp + row * (size_t)(2 * K) + c0 * 2;
  }

  u16x8 pa16[CA]; float4 pa32[CA][2];
  u16x8 pb16[CB]; float4 pb32[CB][4];

  auto fetch = [&]() {
#pragma unroll
    for (int q = 0; q < CA; ++q) {
      if constexpr (AMODE == 0) { pa16[q] = *(const u16x8*)gA16[q]; gA16[q] += 32; }
      else {
        pa32[q][0] = *(const float4*)gA32[q];
        pa32[q][1] = *(const float4*)(gA32[q] + 4);
        gA32[q] += 32;
      }
    }
#pragma unroll
    for (int q = 0; q < CB; ++q) {
      if constexpr (BMODE == 0) { pb16[q] = *(const u16x8*)gB16[q]; gB16[q] += 32; }
      else if constexpr (BMODE == 1) {
        pb32[q][0] = *(const float4*)gB32[q];
        pb32[q][1] = *(const float4*)(gB32[q] + 4);
        gB32[q] += 32;
      } else {
#pragma unroll
        for (int r = 0; r < 4; ++r) pb32[q][r] = *(const float4*)(gB32[q] + 4 * r);
        gB32[q] += 64;
      }
    }
  };

  auto stage = [&]() {
#pragma unroll
    for (int q = 0; q < CA; ++q) {
      u16x8* w = (u16x8*)(As + (sr + q * 64) * 32 + c0);
      if constexpr (AMODE == 0) *w = pa16[q];
      else                      *w = pack8(pa32[q][0], pa32[q][1]);
    }
#pragma unroll
    for (int q = 0; q < CB; ++q) {
      u16x8* w = (u16x8*)(Bs + (sr + q * 64) * 32 + c0);
      if constexpr (BMODE == 0)      *w = pb16[q];
      else if constexpr (BMODE == 1) *w = pack8(pb32[q][0], pb32[q][1]);
      else                           *w = pack8d(pb32[q]);
    }
  };

  const int wm = (wave >> 1) * (BM / 2);
  const int wn = (wave & 1) * (BN / 2);
  const int fr = lane & 15;
  const int koff = (lane >> 4) * 8;

  fetch();                             // prefetch tile 0

  f32x4 acc[MI][NJ];
#pragma unroll
  for (int i = 0; i < MI; ++i)
#pragma unroll
    for (int j = 0; j < NJ; ++j)
      acc[i][j] = (f32x4){0.f, 0.f, 0.f, 0.f};

  const int T = K >> 5;
  for (int k = 0; k < T; ++k) {
    __syncthreads();                   // prev iter's LDS readers done
    stage();
    __syncthreads();                   // LDS tile ready
    if (k + 1 < T) fetch();            // next-tile loads fly across MFMA section

    bf16x8 a[MI], b[NJ];
#pragma unroll
    for (int i = 0; i < MI; ++i)
      a[i] = *(const bf16x8*)(As + (wm + i * 16 + fr) * 32 + koff);
#pragma unroll
    for (int j = 0; j < NJ; ++j)
      b[j] = *(const bf16x8*)(Bs + (wn + j * 16 + fr) * 32 + koff);
#pragma unroll
    for (int i = 0; i < MI; ++i)
#pragma unroll
      for (int j = 0; j < NJ; ++j)
        acc[i][j] = __builtin_amdgcn_mfma_f32_16x16x32_bf16(a[i], b[j], acc[i][j], 0, 0, 0);
  }

  // epilogue: row = wm + i*16 + (lane>>4)*4 + r, col = wn + j*16 + (lane&15)
#pragma unroll
  for (int j = 0; j < NJ; ++j) {
    const int col = bn * BN + wn + j * 16 + fr;
    float bv;
    if constexpr (EP == 0) bv = bias[col];
    else                   bv = bias[2 * col + 1] - bias[2 * col];
#pragma unroll
    for (int i = 0; i < MI; ++i) {
#pragma unroll
      for (int r = 0; r < 4; ++r) {
        const int row = bm * BM + wm + i * 16 + (lane >> 4) * 4 + r;
        const float x = acc[i][j][r] + bv;
        const size_t idx = (size_t)row * N + col;
        if constexpr (EP == 0) {
          outb[idx] = f2bf(tanh_fast(x));
        } else {
          const float att = sigmoid_fast(x);
          outf[idx] = att;
          sa[idx] = f2bf(obs[idx] * att);
        }
      }
    }
  }
}

// ---------------- v = h2[4096,2048] . W3[2048] + b3 : one wave per row ----------------
__global__ __launch_bounds__(256)
void gemv_v(const u16* __restrict__ h2, const float* __restrict__ W3,
            const float* __restrict__ b3, float* __restrict__ out) {
  int g = blockIdx.x * 256 + threadIdx.x;
  int row = g >> 6;
  int lane = g & 63;
  const u16* rp = h2 + (size_t)row * 2048;
  float sum = 0.f;
#pragma unroll
  for (int p = 0; p < 4; ++p) {
    int base = p * 512 + lane * 8;
    u16x8 hv = *(const u16x8*)(rp + base);
    float4 w0 = *(const float4*)(W3 + base);
    float4 w1 = *(const float4*)(W3 + base + 4);
    sum += bf2f(hv[0]) * w0.x + bf2f(hv[1]) * w0.y + bf2f(hv[2]) * w0.z + bf2f(hv[3]) * w0.w;
    sum += bf2f(hv[4]) * w1.x + bf2f(hv[5]) * w1.y + bf2f(hv[6]) * w1.z + bf2f(hv[7]) * w1.w;
  }
#pragma unroll
  for (int off = 32; off > 0; off >>= 1) sum += __shfl_down(sum, off);
  if (lane == 0) out[row] = sum + b3[0];
}

extern "C" void kernel_launch(void* const* d_in, const int* in_sizes, int n_in,
                              void* d_out, int out_size, void* d_ws, size_t ws_size,
                              hipStream_t stream) {
  const float* obs   = (const float*)d_in[0];   // [4096,1024]
  const float* We    = (const float*)d_in[1];   // [512,1024]
  const float* be    = (const float*)d_in[2];   // [512]
  const float* attnW = (const float*)d_in[3];   // [1024,512,2]
  const float* attnb = (const float*)d_in[4];   // [1024,2]
  const float* W1    = (const float*)d_in[5];   // [2048,1024]
  const float* b1    = (const float*)d_in[6];   // [2048]
  const float* W2    = (const float*)d_in[7];   // [2048,2048]
  const float* b2    = (const float*)d_in[8];   // [2048]
  const float* W3    = (const float*)d_in[9];   // [1,2048]
  const float* b3    = (const float*)d_in[10];  // [1]
  float* out = (float*)d_out;                   // [4096] v, then [4096,1024] attention

  char* ws = (char*)d_ws;
  u16* e_b  = (u16*)(ws + 0x0000000);   // 4 MB  [4096,512]
  u16* sa_b = (u16*)(ws + 0x0400000);   // 8 MB  [4096,1024]
  u16* h1_b = (u16*)(ws + 0x0C00000);   // 16 MB [4096,2048]
  u16* h2_b = (u16*)(ws + 0x1C00000);   // 16 MB [4096,2048] (end 44 MB)

  // G1: e = tanh(obs @ We^T + be)  — A fp32-cvt, B fp32-cvt.  512 blocks, 2/CU
  gemm_f<64, 64, 1, 1, 0><<<dim3(64, 8), 256, 0, stream>>>(
      obs, We, 512, 1024, be, e_b, nullptr, nullptr, nullptr);
  // G2: att = sigmoid(e @ Wd^T + bd); sa = obs*att — B = attnW diff-cvt.  512 blocks
  gemm_f<128, 64, 0, 2, 1><<<dim3(32, 16), 256, 0, stream>>>(
      e_b, attnW, 1024, 512, attnb, nullptr, out + 4096, obs, sa_b);
  // G3: h1 = tanh(sa @ W1^T + b1) — B fp32-cvt.  512 blocks, 2/CU
  gemm_f<128, 128, 0, 1, 0><<<dim3(32, 16), 256, 0, stream>>>(
      sa_b, W1, 2048, 1024, b1, h1_b, nullptr, nullptr, nullptr);
  // G4: h2 = tanh(h1 @ W2^T + b2) — B fp32-cvt.  512 blocks, 2/CU
  gemm_f<128, 128, 0, 1, 0><<<dim3(32, 16), 256, 0, stream>>>(
      h1_b, W2, 2048, 2048, b2, h2_b, nullptr, nullptr, nullptr);
  // v = h2 @ W3^T + b3
  gemv_v<<<1024, 256, 0, stream>>>(h2_b, W3, b3, out);
}

// Round 5
// 217.091 us; speedup vs baseline: 1.1714x; 1.1714x over previous
//
#include <hip/hip_runtime.h>
#include <hip/hip_bf16.h>

typedef unsigned short u16;
typedef u16 u16x4 __attribute__((ext_vector_type(4)));
typedef u16 u16x8 __attribute__((ext_vector_type(8)));
typedef __bf16 bf16x8 __attribute__((ext_vector_type(8)));
typedef float f32x4 __attribute__((ext_vector_type(4)));

__device__ __forceinline__ u16 f2bf(float f) {
  unsigned u = __float_as_uint(f);
  u += 0x7FFFu + ((u >> 16) & 1u);   // round-to-nearest-even
  return (u16)(u >> 16);
}
__device__ __forceinline__ float bf2f(u16 h) {
  return __uint_as_float(((unsigned)h) << 16);
}
__device__ __forceinline__ float tanh_fast(float x) {
  float t = __expf(2.0f * x);
  return 1.0f - 2.0f / (t + 1.0f);
}
__device__ __forceinline__ float sigmoid_fast(float x) {
  return 1.0f / (1.0f + __expf(-x));
}

// ---------------- fused prep: all fp32->bf16 casts + attn weight-diff ----------------
// Weights are converted ONCE here (R4 lesson: fusing cvt into GEMM staging
// re-converts per M-block and doubles staged bytes -> big regression).
__device__ __forceinline__ void cvt4(const float* __restrict__ s, u16* __restrict__ d, int q) {
  float4 v = ((const float4*)s)[q];
  u16x4 o = { f2bf(v.x), f2bf(v.y), f2bf(v.z), f2bf(v.w) };
  ((u16x4*)d)[q] = o;
}

__global__ __launch_bounds__(256)
void prep_kernel(const float* __restrict__ obs, const float* __restrict__ We,
                 const float* __restrict__ W1, const float* __restrict__ W2,
                 const float* __restrict__ aW, const float* __restrict__ ab,
                 u16* __restrict__ obs_b, u16* __restrict__ We_b,
                 u16* __restrict__ W1_b, u16* __restrict__ W2_b,
                 u16* __restrict__ Wd, float* __restrict__ bd) {
  int q = blockIdx.x * 256 + threadIdx.x;          // quad (4-element) index
  if (q < 1048576) { cvt4(obs, obs_b, q); return; }                 // 4096*1024
  q -= 1048576;
  if (q < 131072) { cvt4(We, We_b, q); return; }                    // 512*1024
  q -= 131072;
  if (q < 524288) { cvt4(W1, W1_b, q); return; }                    // 2048*1024
  q -= 524288;
  if (q < 1048576) { cvt4(W2, W2_b, q); return; }                   // 2048*2048
  q -= 1048576;
  if (q < 131072) {                                                  // Wd: 1024*512
    int i0 = q * 4;
    int o = i0 >> 9, e0 = i0 & 511;
    const float* p = aW + (size_t)o * 1024 + e0 * 2;
    float4 v0 = *(const float4*)p;
    float4 v1 = *(const float4*)(p + 4);
    u16x4 od = { f2bf(v0.y - v0.x), f2bf(v0.w - v0.z),
                 f2bf(v1.y - v1.x), f2bf(v1.w - v1.z) };
    *(u16x4*)(Wd + i0) = od;
    if (q < 256) {                                                   // bd: 1024
      float4 a0 = *(const float4*)(ab + q * 8);
      float4 a1 = *(const float4*)(ab + q * 8 + 4);
      float4 ob = { a0.y - a0.x, a0.w - a0.z, a1.y - a1.x, a1.w - a1.z };
      *(float4*)(bd + q * 4) = ob;
    }
  }
}

// ---------------- bf16 MFMA GEMM, C = A[M,K] * Bt[N,K]^T ----------------
// R2-proven core: VGPR-pipelined staging — tile k+1 loads issue right after
// the LDS-ready barrier and fly across the whole ds_read+MFMA section; the
// forced vmcnt(0)-before-barrier coincides with ds_write needing the regs.
// EP 0: outb = bf16(tanh(x + bias[col]))
// EP 1: att = sigmoid(x + bias[col]); outf = att; sa = bf16(obs * att)
// EP 2: x = tanh(x + bias[col]); fused v-dot: atomicAdd(vout[row], sum_col x*W3[col])
//       (no C store at all — h2 never touches global memory)
template <int BM, int BN, int EP>
__global__ __launch_bounds__(256)
void gemm_bt(const u16* __restrict__ A, const u16* __restrict__ Bt,
             int N, int K,
             const float* __restrict__ bias,
             u16* __restrict__ outb, float* __restrict__ outf,
             const float* __restrict__ obs, u16* __restrict__ sa,
             const float* __restrict__ W3, const float* __restrict__ b3,
             float* __restrict__ vout) {
  constexpr int CA = BM / 64;          // staging chunks per thread (A)
  constexpr int CB = BN / 64;          // staging chunks per thread (B)
  constexpr int MI = BM / 32;          // 16-row frags per wave
  constexpr int NJ = BN / 32;          // 16-col frags per wave

  __shared__ __align__(16) u16 As[BM * 32];
  __shared__ __align__(16) u16 Bs[BN * 32];

  const int tid = threadIdx.x;
  const int lane = tid & 63;
  const int wave = tid >> 6;
  const int bm = blockIdx.x, bn = blockIdx.y;

  const int sr = tid >> 2;             // staging row 0..63
  const int c0 = (tid & 3) * 8;        // element offset in 32-wide K slab

  const u16* gA[CA];
  const u16* gB[CB];
#pragma unroll
  for (int q = 0; q < CA; ++q)
    gA[q] = A + (size_t)(bm * BM + sr + q * 64) * K + c0;
#pragma unroll
  for (int q = 0; q < CB; ++q)
    gB[q] = Bt + (size_t)(bn * BN + sr + q * 64) * K + c0;

  u16x8 pa[CA], pb[CB];
#pragma unroll
  for (int q = 0; q < CA; ++q) { pa[q] = *(const u16x8*)gA[q]; gA[q] += 32; }
#pragma unroll
  for (int q = 0; q < CB; ++q) { pb[q] = *(const u16x8*)gB[q]; gB[q] += 32; }

  const int wm = (wave >> 1) * (BM / 2);
  const int wn = (wave & 1) * (BN / 2);
  const int fr = lane & 15;
  const int koff = (lane >> 4) * 8;

  f32x4 acc[MI][NJ];
#pragma unroll
  for (int i = 0; i < MI; ++i)
#pragma unroll
    for (int j = 0; j < NJ; ++j)
      acc[i][j] = (f32x4){0.f, 0.f, 0.f, 0.f};

  const int T = K >> 5;
  for (int k = 0; k < T; ++k) {
    __syncthreads();                   // prev iter's LDS readers done (+vmcnt drain)
#pragma unroll
    for (int q = 0; q < CA; ++q) *(u16x8*)(As + (sr + q * 64) * 32 + c0) = pa[q];
#pragma unroll
    for (int q = 0; q < CB; ++q) *(u16x8*)(Bs + (sr + q * 64) * 32 + c0) = pb[q];
    __syncthreads();                   // LDS tile ready

    if (k + 1 < T) {                   // next-tile loads fly across MFMA section
#pragma unroll
      for (int q = 0; q < CA; ++q) { pa[q] = *(const u16x8*)gA[q]; gA[q] += 32; }
#pragma unroll
      for (int q = 0; q < CB; ++q) { pb[q] = *(const u16x8*)gB[q]; gB[q] += 32; }
    }

    bf16x8 a[MI], b[NJ];
#pragma unroll
    for (int i = 0; i < MI; ++i)
      a[i] = *(const bf16x8*)(As + (wm + i * 16 + fr) * 32 + koff);
#pragma unroll
    for (int j = 0; j < NJ; ++j)
      b[j] = *(const bf16x8*)(Bs + (wn + j * 16 + fr) * 32 + koff);
#pragma unroll
    for (int i = 0; i < MI; ++i)
#pragma unroll
      for (int j = 0; j < NJ; ++j)
        acc[i][j] = __builtin_amdgcn_mfma_f32_16x16x32_bf16(a[i], b[j], acc[i][j], 0, 0, 0);
  }

  // epilogue: row = bm*BM + wm + i*16 + (lane>>4)*4 + r, col = bn*BN + wn + j*16 + fr
  if constexpr (EP == 2) {
    float vpart[MI][4];
#pragma unroll
    for (int i = 0; i < MI; ++i)
#pragma unroll
      for (int r = 0; r < 4; ++r) vpart[i][r] = 0.f;
#pragma unroll
    for (int j = 0; j < NJ; ++j) {
      const int col = bn * BN + wn + j * 16 + fr;
      const float bv = bias[col];
      const float w3 = W3[col];
#pragma unroll
      for (int i = 0; i < MI; ++i)
#pragma unroll
        for (int r = 0; r < 4; ++r)
          vpart[i][r] += tanh_fast(acc[i][j][r] + bv) * w3;
    }
    const bool lead = (fr == 0);
    const bool addb = (bn == 0) && ((wave & 1) == 0);
#pragma unroll
    for (int i = 0; i < MI; ++i)
#pragma unroll
      for (int r = 0; r < 4; ++r) {
        float p = vpart[i][r];
        p += __shfl_xor(p, 8);
        p += __shfl_xor(p, 4);
        p += __shfl_xor(p, 2);
        p += __shfl_xor(p, 1);
        if (lead) {
          const int row = bm * BM + wm + i * 16 + (lane >> 4) * 4 + r;
          atomicAdd(vout + row, addb ? p + b3[0] : p);
        }
      }
  } else {
#pragma unroll
    for (int j = 0; j < NJ; ++j) {
      const int col = bn * BN + wn + j * 16 + fr;
      const float bv = bias[col];
#pragma unroll
      for (int i = 0; i < MI; ++i) {
#pragma unroll
        for (int r = 0; r < 4; ++r) {
          const int row = bm * BM + wm + i * 16 + (lane >> 4) * 4 + r;
          const float x = acc[i][j][r] + bv;
          const size_t idx = (size_t)row * N + col;
          if constexpr (EP == 0) {
            outb[idx] = f2bf(tanh_fast(x));
          } else {
            const float att = sigmoid_fast(x);
            outf[idx] = att;
            sa[idx] = f2bf(obs[idx] * att);
          }
        }
      }
    }
  }
}

extern "C" void kernel_launch(void* const* d_in, const int* in_sizes, int n_in,
                              void* d_out, int out_size, void* d_ws, size_t ws_size,
                              hipStream_t stream) {
  const float* obs   = (const float*)d_in[0];   // [4096,1024]
  const float* We    = (const float*)d_in[1];   // [512,1024]
  const float* be    = (const float*)d_in[2];   // [512]
  const float* attnW = (const float*)d_in[3];   // [1024,512,2]
  const float* attnb = (const float*)d_in[4];   // [1024,2]
  const float* W1    = (const float*)d_in[5];   // [2048,1024]
  const float* b1    = (const float*)d_in[6];   // [2048]
  const float* W2    = (const float*)d_in[7];   // [2048,2048]
  const float* b2    = (const float*)d_in[8];   // [2048]
  const float* W3    = (const float*)d_in[9];   // [1,2048]
  const float* b3    = (const float*)d_in[10];  // [1]
  float* out = (float*)d_out;                   // [4096] v, then [4096,1024] attention

  char* ws = (char*)d_ws;
  u16*   We_b  = (u16*)(ws + 0x00000000);   // 1 MB
  u16*   Wd_b  = (u16*)(ws + 0x00100000);   // 1 MB
  u16*   W1_b  = (u16*)(ws + 0x00200000);   // 4 MB
  u16*   W2_b  = (u16*)(ws + 0x00600000);   // 8 MB
  float* bd    = (float*)(ws + 0x00E00000); // 4 KB
  u16*   obs_b = (u16*)(ws + 0x00E01000);   // 8 MB
  u16*   e_b   = (u16*)(ws + 0x01601000);   // 4 MB
  u16*   sa_b  = (u16*)(ws + 0x01A01000);   // 8 MB
  u16*   h1_b  = (u16*)(ws + 0x02201000);   // 16 MB (end ≈ 50 MB; h2 never materialized)

  // v accumulates via atomics — zero it (d_out is poisoned before every launch)
  hipMemsetAsync(out, 0, 4096 * sizeof(float), stream);

  // all casts + attn weight prep in ONE launch (2883584 quads)
  prep_kernel<<<11264, 256, 0, stream>>>(obs, We, W1, W2, attnW, attnb,
                                         obs_b, We_b, W1_b, W2_b, Wd_b, bd);

  // G1: e = tanh(obs @ We^T + be)   [4096,512]   128x64 tile -> 256 blocks
  gemm_bt<128, 64, 0><<<dim3(32, 8), 256, 0, stream>>>(
      obs_b, We_b, 512, 1024, be, e_b, nullptr, nullptr, nullptr, nullptr, nullptr, nullptr);
  // G2: att = sigmoid(e @ Wd^T + bd); sa = obs*att   [4096,1024]  128x64 -> 512 blocks
  gemm_bt<128, 64, 1><<<dim3(32, 16), 256, 0, stream>>>(
      e_b, Wd_b, 1024, 512, bd, nullptr, out + 4096, obs, sa_b, nullptr, nullptr, nullptr);
  // G3: h1 = tanh(sa @ W1^T + b1)   [4096,2048]  128x128 -> 512 blocks
  gemm_bt<128, 128, 0><<<dim3(32, 16), 256, 0, stream>>>(
      sa_b, W1_b, 2048, 1024, b1, h1_b, nullptr, nullptr, nullptr, nullptr, nullptr, nullptr);
  // G4+v: v = tanh(h1 @ W2^T + b2) @ W3 + b3 — fused, h2 never stored
  gemm_bt<128, 128, 2><<<dim3(32, 16), 256, 0, stream>>>(
      h1_b, W2_b, 2048, 2048, b2, nullptr, nullptr, nullptr, nullptr, W3, b3, out);
}